// Round 1
// 273.661 us; speedup vs baseline: 1.0838x; 1.0838x over previous
//
#include <hip/hip_runtime.h>

#define Kst 256
#define Dd 256
#define Vv 50000
#define VPAD 50176
#define Tt 512
#define Bb 256
#define KP1 257
#define MD 512
#define NROWS (KP1*KP1)   // 66049
#define EPSf 1e-5f

#define VB2 196           // vocab blocks (256 v each)
#define VB3 (VB2*4)       // per-wave lse partials per k row

typedef __attribute__((ext_vector_type(8))) short short8;
typedef __attribute__((ext_vector_type(4))) short short4v;
typedef __attribute__((ext_vector_type(4))) float f32x4;
typedef __attribute__((ext_vector_type(4))) unsigned u32x4;
typedef __attribute__((ext_vector_type(2))) unsigned u32x2;

__device__ __forceinline__ unsigned short f2bf(float f) {
    unsigned u = __builtin_bit_cast(unsigned, f);
    unsigned r = (u + 0x7fffu + ((u >> 16) & 1u)) >> 16;
    return (unsigned short)r;
}
__device__ __forceinline__ float bf2f(unsigned short u) {
    return __builtin_bit_cast(float, ((unsigned)u) << 16);
}
// truncating pack (MFMA inputs only)
__device__ __forceinline__ unsigned bfpack(float lo, float hi) {
    return __builtin_amdgcn_perm(__builtin_bit_cast(unsigned, hi),
                                 __builtin_bit_cast(unsigned, lo), 0x07060302u);
}
// rounding pack (stores feeding final outputs)
__device__ __forceinline__ unsigned f2bf2(float lo, float hi) {
    return (unsigned)f2bf(lo) | ((unsigned)f2bf(hi) << 16);
}

// ---------------- K_hP: MFMA preprocessing (unchanged) ----------------
__global__ __launch_bounds__(256) void k_hP(
    const float* __restrict__ lembs, const float* __restrict__ em_W,
    const float* __restrict__ em_bias, const float* __restrict__ em_g,
    const float* __restrict__ em_beta, unsigned short* __restrict__ h_bf,
    const float* __restrict__ tlembs, const float* __restrict__ tm_W,
    float* __restrict__ P0, float* __restrict__ P1,
    const float* __restrict__ td_W, const float* __restrict__ tn_g,
    const float* __restrict__ tn_beta, const float* __restrict__ td_b,
    unsigned short* __restrict__ tdwg_bf, float* __restrict__ Gt,
    float* __restrict__ Bt)
{
    int bid = blockIdx.x;
    int tid = threadIdx.x, lane = tid & 63, wv = tid >> 6;
    int l15 = lane & 15, q = lane >> 4;

    if (bid >= 44) {
        int c = (bid - 44)*4 + wv;
        const float4* w4 = (const float4*)(td_W + (size_t)c*MD);
        const float4* g4 = (const float4*)tn_g;
        const float4* b4 = (const float4*)tn_beta;
        float sg = 0.f, sb = 0.f;
        short8 o;
        #pragma unroll
        for (int u = 0; u < 2; ++u) {
            int j4 = lane*2 + u;
            float4 w = w4[j4], g = g4[j4], bt = b4[j4];
            sg += w.x*g.x + w.y*g.y + w.z*g.z + w.w*g.w;
            sb += w.x*bt.x + w.y*bt.y + w.z*bt.z + w.w*bt.w;
            o[u*4+0] = (short)f2bf(w.x*g.x);
            o[u*4+1] = (short)f2bf(w.y*g.y);
            o[u*4+2] = (short)f2bf(w.z*g.z);
            o[u*4+3] = (short)f2bf(w.w*g.w);
        }
        *(short8*)(tdwg_bf + (size_t)c*MD + lane*8) = o;
        #pragma unroll
        for (int dd = 32; dd > 0; dd >>= 1) {
            sg += __shfl_xor(sg, dd);
            sb += __shfl_xor(sb, dd);
        }
        if (lane == 0) { Gt[c] = sg; Bt[c] = sb + td_b[c]; }
        return;
    }

    __shared__ short ta[32][264];
    __shared__ float lsep[4][32][2];
    __shared__ float musig[32][2];

    int job, r0, cb, koff, BK;
    const float* Arow; const float* Brow;
    if (bid < 8) {
        job = 0; r0 = bid*32; cb = 0; koff = 0; BK = Dd;
        Arow = lembs; Brow = em_W;
    } else {
        int b2 = bid - 8;
        int half = b2 / 18;
        int b3 = b2 % 18;
        job = 1 + half;
        r0 = (b3 >> 1) * 32;
        cb = (b3 & 1) * 256;
        koff = half * 256; BK = MD;
        Arow = tlembs; Brow = tm_W;
    }

    {
        int row = tid >> 3, seg = (tid & 7) * 32;
        int r = r0 + row;
        if (r > 256) r = 256;
        const float4* s4 = (const float4*)(Arow + (size_t)r*Dd + seg);
        #pragma unroll
        for (int u = 0; u < 4; ++u) {
            float4 f0 = s4[u*2], f1 = s4[u*2+1];
            u32x4 pk;
            pk.x = bfpack(f0.x, f0.y);
            pk.y = bfpack(f0.z, f0.w);
            pk.z = bfpack(f1.x, f1.y);
            pk.w = bfpack(f1.z, f1.w);
            *(short8*)&ta[row][seg + u*8] = __builtin_bit_cast(short8, pk);
        }
    }
    __syncthreads();

    const float* bptr[4];
    #pragma unroll
    for (int ct = 0; ct < 4; ++ct) {
        int j = cb + wv*64 + ct*16 + l15;
        bptr[ct] = Brow + (size_t)j*BK + koff + q*8;
    }
    f32x4 acc[2][4];
    #pragma unroll
    for (int rt = 0; rt < 2; ++rt)
        #pragma unroll
        for (int ct = 0; ct < 4; ++ct)
            acc[rt][ct] = (f32x4){0.f,0.f,0.f,0.f};
    for (int ks = 0; ks < 8; ++ks) {
        short8 a0 = *(const short8*)&ta[ 0 + l15][ks*32 + q*8];
        short8 a1 = *(const short8*)&ta[16 + l15][ks*32 + q*8];
        short8 b[4];
        #pragma unroll
        for (int ct = 0; ct < 4; ++ct) {
            float4 f0 = *(const float4*)(bptr[ct] + ks*32);
            float4 f1 = *(const float4*)(bptr[ct] + ks*32 + 4);
            u32x4 pk;
            pk.x = bfpack(f0.x, f0.y);
            pk.y = bfpack(f0.z, f0.w);
            pk.z = bfpack(f1.x, f1.y);
            pk.w = bfpack(f1.z, f1.w);
            b[ct] = __builtin_bit_cast(short8, pk);
        }
        #pragma unroll
        for (int ct = 0; ct < 4; ++ct) {
            acc[0][ct] = __builtin_amdgcn_mfma_f32_16x16x32_bf16(a0, b[ct], acc[0][ct], 0,0,0);
            acc[1][ct] = __builtin_amdgcn_mfma_f32_16x16x32_bf16(a1, b[ct], acc[1][ct], 0,0,0);
        }
    }

    if (job != 0) {
        float* Pd = (job == 1) ? P0 : P1;
        #pragma unroll
        for (int rt = 0; rt < 2; ++rt) {
            #pragma unroll
            for (int reg = 0; reg < 4; ++reg) {
                int r = r0 + rt*16 + q*4 + reg;
                if (r < KP1) {
                    float* dst = Pd + (size_t)r*MD + cb + wv*64;
                    #pragma unroll
                    for (int ct = 0; ct < 4; ++ct)
                        dst[ct*16 + l15] = acc[rt][ct][reg];
                }
            }
        }
        return;
    }

    float bias_c[4];
    #pragma unroll
    for (int ct = 0; ct < 4; ++ct)
        bias_c[ct] = em_bias[wv*64 + ct*16 + l15];
    #pragma unroll
    for (int rt = 0; rt < 2; ++rt) {
        #pragma unroll
        for (int reg = 0; reg < 4; ++reg) {
            int r = r0 + rt*16 + q*4 + reg;
            #pragma unroll
            for (int ct = 0; ct < 4; ++ct) {
                float lv = lembs[(size_t)r*Dd + wv*64 + ct*16 + l15];
                acc[rt][ct][reg] = lv + fmaxf(acc[rt][ct][reg] + bias_c[ct], 0.f);
            }
        }
    }
    #pragma unroll
    for (int rt = 0; rt < 2; ++rt) {
        #pragma unroll
        for (int reg = 0; reg < 4; ++reg) {
            float s  = ((acc[rt][0][reg] + acc[rt][1][reg]) + (acc[rt][2][reg] + acc[rt][3][reg]));
            float ss = ((acc[rt][0][reg]*acc[rt][0][reg] + acc[rt][1][reg]*acc[rt][1][reg])
                      + (acc[rt][2][reg]*acc[rt][2][reg] + acc[rt][3][reg]*acc[rt][3][reg]));
            s  += __shfl_xor(s, 1);  ss += __shfl_xor(ss, 1);
            s  += __shfl_xor(s, 2);  ss += __shfl_xor(ss, 2);
            s  += __shfl_xor(s, 4);  ss += __shfl_xor(ss, 4);
            s  += __shfl_xor(s, 8);  ss += __shfl_xor(ss, 8);
            if (l15 == 0) {
                int rw = rt*16 + q*4 + reg;
                lsep[wv][rw][0] = s;
                lsep[wv][rw][1] = ss;
            }
        }
    }
    __syncthreads();
    if (tid < 32) {
        float s  = (lsep[0][tid][0] + lsep[1][tid][0]) + (lsep[2][tid][0] + lsep[3][tid][0]);
        float ss = (lsep[0][tid][1] + lsep[1][tid][1]) + (lsep[2][tid][1] + lsep[3][tid][1]);
        float mu = s * (1.f/Dd);
        musig[tid][0] = mu;
        musig[tid][1] = rsqrtf(ss*(1.f/Dd) - mu*mu + EPSf);
    }
    __syncthreads();
    float gl[4], bl[4];
    #pragma unroll
    for (int ct = 0; ct < 4; ++ct) {
        gl[ct] = em_g[wv*64 + ct*16 + l15];
        bl[ct] = em_beta[wv*64 + ct*16 + l15];
    }
    #pragma unroll
    for (int rt = 0; rt < 2; ++rt) {
        #pragma unroll
        for (int reg = 0; reg < 4; ++reg) {
            int rw = rt*16 + q*4 + reg;
            int r = r0 + rw;
            float mu = musig[rw][0], rs = musig[rw][1];
            unsigned short* dst = h_bf + (size_t)r*Dd + wv*64;
            #pragma unroll
            for (int ct = 0; ct < 4; ++ct)
                dst[ct*16 + l15] = f2bf((acc[rt][ct][reg] - mu)*rs*gl[ct] + bl[ct]);
        }
    }
}

// ---------------- K_em (MFMA): permuted B cols, prefetch, packed stores ----------------
__global__ __launch_bounds__(256) void k_em_mfma5(
    const float* __restrict__ dec_W, const float* __restrict__ dec_b,
    const unsigned short* __restrict__ h_bf, float* __restrict__ part,
    unsigned short* __restrict__ E2)
{
    int kg = blockIdx.x, vb = blockIdx.y;   // kg fastest: adjacent blocks share dec_W slice
    int tid = threadIdx.x, lane = tid & 63, wv = tid >> 6;
    int l15 = lane & 15, q = lane >> 4;
    __shared__ short hs[64][264];

    {
        int row = tid >> 2, c0 = (tid & 3) * 64;
        const short8* src = (const short8*)(h_bf + (size_t)(kg*64 + row)*Dd + c0);
        #pragma unroll
        for (int u = 0; u < 8; ++u)
            *(short8*)&hs[row][c0 + u*8] = src[u];
    }
    __syncthreads();

    // column permutation: ct-th column of fragment = vb*256 + wv*64 + l15*4 + ct (contiguous per thread)
    const float* bptr[4];
    int vcol[4]; bool vok[4];
    #pragma unroll
    for (int ct = 0; ct < 4; ++ct) {
        int v = vb*256 + wv*64 + l15*4 + ct;
        vok[ct] = (v < Vv);
        if (v > Vv-1) v = Vv-1;
        vcol[ct] = v;
        bptr[ct] = dec_W + (size_t)v*Dd + q*8;
    }
    f32x4 acc[4][4];
    #pragma unroll
    for (int mt = 0; mt < 4; ++mt)
        #pragma unroll
        for (int ct = 0; ct < 4; ++ct)
            acc[mt][ct] = (f32x4){0.f,0.f,0.f,0.f};

    // prefetch double-buffer for B (f32)
    float4 nf[4][2];
    #pragma unroll
    for (int ct = 0; ct < 4; ++ct) {
        nf[ct][0] = *(const float4*)(bptr[ct]);
        nf[ct][1] = *(const float4*)(bptr[ct] + 4);
    }
    #pragma unroll
    for (int ks = 0; ks < 8; ++ks) {
        short8 b[4];
        #pragma unroll
        for (int ct = 0; ct < 4; ++ct) {
            u32x4 pk;
            pk.x = bfpack(nf[ct][0].x, nf[ct][0].y);
            pk.y = bfpack(nf[ct][0].z, nf[ct][0].w);
            pk.z = bfpack(nf[ct][1].x, nf[ct][1].y);
            pk.w = bfpack(nf[ct][1].z, nf[ct][1].w);
            b[ct] = __builtin_bit_cast(short8, pk);
        }
        if (ks < 7) {
            #pragma unroll
            for (int ct = 0; ct < 4; ++ct) {
                nf[ct][0] = *(const float4*)(bptr[ct] + (ks+1)*32);
                nf[ct][1] = *(const float4*)(bptr[ct] + (ks+1)*32 + 4);
            }
        }
        short8 a[4];
        #pragma unroll
        for (int mt = 0; mt < 4; ++mt)
            a[mt] = *(const short8*)&hs[mt*16 + l15][ks*32 + q*8];
        #pragma unroll
        for (int mt = 0; mt < 4; ++mt)
            #pragma unroll
            for (int ct = 0; ct < 4; ++ct)
                acc[mt][ct] = __builtin_amdgcn_mfma_f32_16x16x32_bf16(a[mt], b[ct], acc[mt][ct], 0,0,0);
    }

    #pragma unroll
    for (int ct = 0; ct < 4; ++ct) {
        if (vok[ct]) {
            float db = dec_b[vcol[ct]];
            #pragma unroll
            for (int mt = 0; mt < 4; ++mt)
                #pragma unroll
                for (int reg = 0; reg < 4; ++reg)
                    acc[mt][ct][reg] += db;
        } else {
            #pragma unroll
            for (int mt = 0; mt < 4; ++mt)
                #pragma unroll
                for (int reg = 0; reg < 4; ++reg)
                    acc[mt][ct][reg] = -1e30f;
        }
    }
    // packed 8B stores (pad region of E2 absorbs invalid cols; gather never reads v>=Vv)
    #pragma unroll
    for (int mt = 0; mt < 4; ++mt) {
        #pragma unroll
        for (int reg = 0; reg < 4; ++reg) {
            int k = kg*64 + mt*16 + q*4 + reg;
            u32x2 p;
            p.x = f2bf2(acc[mt][0][reg], acc[mt][1][reg]);
            p.y = f2bf2(acc[mt][2][reg], acc[mt][3][reg]);
            *(u32x2*)(E2 + (size_t)k*VPAD + vb*256 + wv*64 + l15*4) = p;
        }
    }
    #pragma unroll
    for (int mt = 0; mt < 4; ++mt) {
        #pragma unroll
        for (int reg = 0; reg < 4; ++reg) {
            float m = fmaxf(fmaxf(acc[mt][0][reg], acc[mt][1][reg]),
                            fmaxf(acc[mt][2][reg], acc[mt][3][reg]));
            m = fmaxf(m, __shfl_xor(m, 1));
            m = fmaxf(m, __shfl_xor(m, 2));
            m = fmaxf(m, __shfl_xor(m, 4));
            m = fmaxf(m, __shfl_xor(m, 8));
            float s = __expf(acc[mt][0][reg] - m) + __expf(acc[mt][1][reg] - m)
                    + __expf(acc[mt][2][reg] - m) + __expf(acc[mt][3][reg] - m);
            s += __shfl_xor(s, 1);
            s += __shfl_xor(s, 2);
            s += __shfl_xor(s, 4);
            s += __shfl_xor(s, 8);
            if (l15 == 0) {
                int k = kg*64 + mt*16 + q*4 + reg;
                part[((size_t)k*VB3 + vb*4 + wv)*2]     = m;
                part[((size_t)k*VB3 + vb*4 + wv)*2 + 1] = s;
            }
        }
    }
}

// ---------------- K_comb: combine partials -> lse_em[k] (unchanged) ----------------
__global__ __launch_bounds__(64) void k_em_comb3(
    const float* __restrict__ part, float* __restrict__ lse_em)
{
    int k = blockIdx.x, lane = threadIdx.x;
    float m = -1e30f, s = 0.f;
    for (int vb = lane; vb < VB3; vb += 64) {
        float m2 = part[((size_t)k*VB3+vb)*2], s2 = part[((size_t)k*VB3+vb)*2+1];
        if (m2 > m) { s = s*__expf(m - m2) + s2; m = m2; }
        else          s += s2*__expf(m2 - m);
    }
    #pragma unroll
    for (int d = 1; d < 64; d <<= 1) {
        float mo = __shfl_xor(m, d), so = __shfl_xor(s, d);
        float mn = fmaxf(m, mo);
        s = s*__expf(m - mn) + so*__expf(mo - mn);
        m = mn;
    }
    if (lane == 0) lse_em[k] = m + logf(s);
}

// ---------------- K_trans9: fused stats in stage, 2 barriers, B prefetch, packed stores ----------------
__global__ __launch_bounds__(256, 4) void k_trans9(
    const float* __restrict__ tlembs, const float* __restrict__ P0,
    const float* __restrict__ P1, const float* __restrict__ tm_bias,
    const short* __restrict__ tdwg_bf, const float* __restrict__ Gt,
    const float* __restrict__ Bt, float* __restrict__ lse_t,
    unsigned short* __restrict__ Td)
{
    __shared__ short th[32][520];
    __shared__ float musig[32][2];
    __shared__ float lsep[4][32][2];
    int tid = threadIdx.x, lane = tid & 63, wv = tid >> 6;
    int l15 = lane & 15, q = lane >> 4;
    int r0 = blockIdx.x * 32;

    // ---- stage + LN stats fused (f32 butterfly, no LDS re-read phase) ----
    {
        const float4* bias0 = (const float4*)tm_bias;
        const float4* bias1 = (const float4*)(tm_bias + 256);
        float4 c0 = bias0[lane], c1 = bias1[lane];
        #pragma unroll
        for (int i = 0; i < 8; ++i) {
            int row = wv*8 + i;
            int r = r0 + row; if (r >= NROWS) r = NROWS - 1;
            int i0 = r / KP1, i1 = r - i0*KP1;
            float4 a0 = ((const float4*)(P0 + (size_t)i0*MD))[lane];
            float4 b0 = ((const float4*)(P1 + (size_t)i1*MD))[lane];
            float4 t0 = ((const float4*)(tlembs + (size_t)i0*Dd))[lane];
            float4 a1 = ((const float4*)(P0 + (size_t)i0*MD + 256))[lane];
            float4 b1 = ((const float4*)(P1 + (size_t)i1*MD + 256))[lane];
            float4 t1 = ((const float4*)(tlembs + (size_t)i1*Dd))[lane];
            float v0 = t0.x + fmaxf(a0.x+b0.x+c0.x, 0.f);
            float v1 = t0.y + fmaxf(a0.y+b0.y+c0.y, 0.f);
            float v2 = t0.z + fmaxf(a0.z+b0.z+c0.z, 0.f);
            float v3 = t0.w + fmaxf(a0.w+b0.w+c0.w, 0.f);
            float v4 = t1.x + fmaxf(a1.x+b1.x+c1.x, 0.f);
            float v5 = t1.y + fmaxf(a1.y+b1.y+c1.y, 0.f);
            float v6 = t1.z + fmaxf(a1.z+b1.z+c1.z, 0.f);
            float v7 = t1.w + fmaxf(a1.w+b1.w+c1.w, 0.f);
            u32x2 p0; p0.x = bfpack(v0, v1); p0.y = bfpack(v2, v3);
            u32x2 p1; p1.x = bfpack(v4, v5); p1.y = bfpack(v6, v7);
            *(u32x2*)&th[row][lane*4]       = p0;
            *(u32x2*)&th[row][256 + lane*4] = p1;
            float s  = ((v0+v1)+(v2+v3)) + ((v4+v5)+(v6+v7));
            float ss = ((v0*v0+v1*v1)+(v2*v2+v3*v3)) + ((v4*v4+v5*v5)+(v6*v6+v7*v7));
            #pragma unroll
            for (int d = 1; d < 64; d <<= 1) {
                s  += __shfl_xor(s, d);
                ss += __shfl_xor(ss, d);
            }
            if (lane == 0) {
                float mu = s * (1.f/MD);
                musig[row][0] = mu;
                musig[row][1] = rsqrtf(ss*(1.f/MD) - mu*mu + EPSf);
            }
        }
    }
    __syncthreads();

    // ---- MFMA with permuted B columns (col = wv*64 + l15*4 + ct) + 1-step prefetch ----
    f32x4 acc[2][4];
    #pragma unroll
    for (int rt = 0; rt < 2; ++rt)
        #pragma unroll
        for (int ct = 0; ct < 4; ++ct)
            acc[rt][ct] = (f32x4){0.f, 0.f, 0.f, 0.f};
    const short* bp0 = tdwg_bf + (size_t)(wv*64 + l15*4    )*MD + q*8;
    const short* bp1 = tdwg_bf + (size_t)(wv*64 + l15*4 + 1)*MD + q*8;
    const short* bp2 = tdwg_bf + (size_t)(wv*64 + l15*4 + 2)*MD + q*8;
    const short* bp3 = tdwg_bf + (size_t)(wv*64 + l15*4 + 3)*MD + q*8;
    short8 nb0 = *(const short8*)bp0;
    short8 nb1 = *(const short8*)bp1;
    short8 nb2 = *(const short8*)bp2;
    short8 nb3 = *(const short8*)bp3;
    #pragma unroll
    for (int ks = 0; ks < 16; ++ks) {
        short8 b0 = nb0, b1 = nb1, b2 = nb2, b3 = nb3;
        if (ks < 15) {
            nb0 = *(const short8*)(bp0 + (ks+1)*32);
            nb1 = *(const short8*)(bp1 + (ks+1)*32);
            nb2 = *(const short8*)(bp2 + (ks+1)*32);
            nb3 = *(const short8*)(bp3 + (ks+1)*32);
        }
        int ko = ks*32 + q*8;
        short8 a0 = *(const short8*)&th[ 0 + l15][ko];
        short8 a1 = *(const short8*)&th[16 + l15][ko];
        acc[0][0] = __builtin_amdgcn_mfma_f32_16x16x32_bf16(a0, b0, acc[0][0], 0,0,0);
        acc[1][0] = __builtin_amdgcn_mfma_f32_16x16x32_bf16(a1, b0, acc[1][0], 0,0,0);
        acc[0][1] = __builtin_amdgcn_mfma_f32_16x16x32_bf16(a0, b1, acc[0][1], 0,0,0);
        acc[1][1] = __builtin_amdgcn_mfma_f32_16x16x32_bf16(a1, b1, acc[1][1], 0,0,0);
        acc[0][2] = __builtin_amdgcn_mfma_f32_16x16x32_bf16(a0, b2, acc[0][2], 0,0,0);
        acc[1][2] = __builtin_amdgcn_mfma_f32_16x16x32_bf16(a1, b2, acc[1][2], 0,0,0);
        acc[0][3] = __builtin_amdgcn_mfma_f32_16x16x32_bf16(a0, b3, acc[0][3], 0,0,0);
        acc[1][3] = __builtin_amdgcn_mfma_f32_16x16x32_bf16(a1, b3, acc[1][3], 0,0,0);
    }

    // ---- LN apply + packed contiguous Td stores + softmax partials ----
    float4 Gc = *(const float4*)(Gt + wv*64 + l15*4);
    float4 Bc = *(const float4*)(Bt + wv*64 + l15*4);
    #pragma unroll
    for (int rt = 0; rt < 2; ++rt) {
        #pragma unroll
        for (int reg = 0; reg < 4; ++reg) {
            int rw = rt*16 + q*4 + reg;
            float mu = musig[rw][0], rs = musig[rw][1];
            float e0 = rs*(acc[rt][0][reg] - mu*Gc.x) + Bc.x;
            float e1 = rs*(acc[rt][1][reg] - mu*Gc.y) + Bc.y;
            float e2 = rs*(acc[rt][2][reg] - mu*Gc.z) + Bc.z;
            float e3 = rs*(acc[rt][3][reg] - mu*Gc.w) + Bc.w;
            long r = (long)r0 + rw;
            if (r < NROWS) {
                u32x2 p;
                p.x = f2bf2(e0, e1);
                p.y = f2bf2(e2, e3);
                *(u32x2*)(Td + (size_t)r*Kst + wv*64 + l15*4) = p;
            }
            float m = fmaxf(fmaxf(e0, e1), fmaxf(e2, e3));
            m = fmaxf(m, __shfl_xor(m, 1));
            m = fmaxf(m, __shfl_xor(m, 2));
            m = fmaxf(m, __shfl_xor(m, 4));
            m = fmaxf(m, __shfl_xor(m, 8));
            float s = __expf(e0 - m) + __expf(e1 - m) + __expf(e2 - m) + __expf(e3 - m);
            s += __shfl_xor(s, 1);
            s += __shfl_xor(s, 2);
            s += __shfl_xor(s, 4);
            s += __shfl_xor(s, 8);
            if (l15 == 0) {
                lsep[wv][rw][0] = m;
                lsep[wv][rw][1] = s;
            }
        }
    }
    __syncthreads();
    if (tid < 32) {
        int r = r0 + tid;
        if (r < NROWS) {
            float m0 = lsep[0][tid][0], m1 = lsep[1][tid][0];
            float m2 = lsep[2][tid][0], m3 = lsep[3][tid][0];
            float mg = fmaxf(fmaxf(m0, m1), fmaxf(m2, m3));
            float s = lsep[0][tid][1]*__expf(m0-mg) + lsep[1][tid][1]*__expf(m1-mg)
                    + lsep[2][tid][1]*__expf(m2-mg) + lsep[3][tid][1]*__expf(m3-mg);
            lse_t[r] = mg + logf(s);
        }
    }
}

// ---------------- K_gather: 4 timesteps per thread, 1 atomic ----------------
#define GT_CH 4
__global__ __launch_bounds__(256) void k_gather3(
    const int* __restrict__ x, const int* __restrict__ z,
    const unsigned short* __restrict__ E2, const float* __restrict__ lse_em,
    const unsigned short* __restrict__ Td, const float* __restrict__ lse_t,
    float* __restrict__ out)
{
    int b = threadIdx.x;
    int t0 = blockIdx.x * GT_CH;
    float accv = 0.f;
    #pragma unroll
    for (int u = 0; u < GT_CH; ++u) {
        int t = t0 + u;
        int zc = z[t*Bb + b];
        int xv = x[t*Bb + b];
        int i0 = (t >= 2) ? z[(t-2)*Bb + b] : Kst;
        int i1 = (t >= 1) ? z[(t-1)*Bb + b] : Kst;
        int lin = i0*KP1 + i1;
        accv += bf2f(E2[(size_t)zc*VPAD + xv]) - lse_em[zc]
              + bf2f(Td[(size_t)lin*Kst + zc]) - lse_t[lin];
    }
    atomicAdd(&out[b], accv);
}

extern "C" void kernel_launch(void* const* d_in, const int* in_sizes, int n_in,
                              void* d_out, int out_size, void* d_ws, size_t ws_size,
                              hipStream_t stream)
{
    const int*   x       = (const int*)  d_in[0];
    const int*   z       = (const int*)  d_in[1];
    const float* lembs   = (const float*)d_in[2];
    const float* tlembs  = (const float*)d_in[3];
    const float* dec_W   = (const float*)d_in[4];
    const float* dec_b   = (const float*)d_in[5];
    const float* em_W    = (const float*)d_in[6];
    const float* em_bias = (const float*)d_in[7];
    const float* em_g    = (const float*)d_in[8];
    const float* em_beta = (const float*)d_in[9];
    const float* td_W    = (const float*)d_in[10];
    const float* td_b    = (const float*)d_in[11];
    const float* tm_W    = (const float*)d_in[12];
    const float* tm_bias = (const float*)d_in[13];
    const float* tn_g    = (const float*)d_in[14];
    const float* tn_beta = (const float*)d_in[15];
    float* out = (float*)d_out;

    float* ws     = (float*)d_ws;
    float* P0     = ws;                    // 131584
    float* P1     = P0 + 131584;           // 131584
    float* lse_em = P1 + 131584;           // 256
    float* part   = lse_em + 256;          // 256*784*2 = 401408
    float* lse_t  = part + 401408;         // 66052
    float* Gt     = lse_t + 66052;         // 256
    float* Bt     = Gt + 256;              // 256
    unsigned short* tdwg_bf = (unsigned short*)(Bt + 256);      // 131072 ushort
    unsigned short* h_bf   = tdwg_bf + 131072;                  // 65536 ushort
    unsigned short* E2     = h_bf + 65536;                      // 256*50176 ushort (25.7MB)
    unsigned short* Td     = E2 + (size_t)Kst*VPAD;             // 66049*256 ushort (33.8MB)

    hipMemsetAsync(out, 0, Bb*sizeof(float), stream);
    k_hP<<<108, 256, 0, stream>>>(lembs, em_W, em_bias, em_g, em_beta, h_bf,
                                  tlembs, tm_W, P0, P1,
                                  td_W, tn_g, tn_beta, td_b, tdwg_bf, Gt, Bt);
    k_em_mfma5<<<dim3(4, VB2), 256, 0, stream>>>(dec_W, dec_b, h_bf, part, E2);
    k_em_comb3<<<Kst, 64, 0, stream>>>(part, lse_em);
    k_trans9<<<(NROWS + 31)/32, 256, 0, stream>>>(tlembs, P0, P1, tm_bias,
                                                  (const short*)tdwg_bf, Gt, Bt,
                                                  lse_t, Td);
    k_gather3<<<Tt/GT_CH, 256, 0, stream>>>(x, z, E2, lse_em, Td, lse_t, out);
}

// Round 2
// 233.376 us; speedup vs baseline: 1.2709x; 1.1726x over previous
//
#include <hip/hip_runtime.h>

#define Kst 256
#define Dd 256
#define Vv 50000
#define VPAD 50176
#define Tt 512
#define Bb 256
#define KP1 257
#define MD 512
#define NROWS (KP1*KP1)   // 66049
#define EPSf 1e-5f

#define VB2 196           // vocab blocks (256 v each)
#define VB3 (VB2*4)       // per-wave lse partials per k row

typedef __attribute__((ext_vector_type(8))) short short8;
typedef __attribute__((ext_vector_type(4))) float f32x4;
typedef __attribute__((ext_vector_type(4))) unsigned u32x4;
typedef __attribute__((ext_vector_type(2))) unsigned u32x2;

__device__ __forceinline__ unsigned short f2bf(float f) {
    unsigned u = __builtin_bit_cast(unsigned, f);
    unsigned r = (u + 0x7fffu + ((u >> 16) & 1u)) >> 16;
    return (unsigned short)r;
}
__device__ __forceinline__ float bf2f(unsigned short u) {
    return __builtin_bit_cast(float, ((unsigned)u) << 16);
}
// truncating pack (MFMA inputs only)
__device__ __forceinline__ unsigned bfpack(float lo, float hi) {
    return __builtin_amdgcn_perm(__builtin_bit_cast(unsigned, hi),
                                 __builtin_bit_cast(unsigned, lo), 0x07060302u);
}
// rounding pack (stores feeding final outputs)
__device__ __forceinline__ unsigned f2bf2(float lo, float hi) {
    return (unsigned)f2bf(lo) | ((unsigned)f2bf(hi) << 16);
}

// ---------------- K_hP: MFMA preprocessing ----------------
// bid [44,108): tdwg now written in MFMA-FRAGMENT layout:
//   tdwgP[((wv*16+ks)*4+ct)*64 + (q*16+l15)] : short8  (value = td_W[col][k]*g[k],
//   col = wv*64+l15*4+ct, k = ks*32+q*8+e)  -> k_trans B-loads are 1KB contiguous.
__global__ __launch_bounds__(256) void k_hP(
    const float* __restrict__ lembs, const float* __restrict__ em_W,
    const float* __restrict__ em_bias, const float* __restrict__ em_g,
    const float* __restrict__ em_beta, unsigned short* __restrict__ h_bf,
    const float* __restrict__ tlembs, const float* __restrict__ tm_W,
    float* __restrict__ P0, float* __restrict__ P1,
    const float* __restrict__ td_W, const float* __restrict__ tn_g,
    const float* __restrict__ tn_beta, const float* __restrict__ td_b,
    unsigned short* __restrict__ tdwg_bf, float* __restrict__ Gt,
    float* __restrict__ Bt)
{
    int bid = blockIdx.x;
    int tid = threadIdx.x, lane = tid & 63, wv = tid >> 6;
    int l15 = lane & 15, q = lane >> 4;

    if (bid >= 44) {
        int c = (bid - 44)*4 + wv;
        const float4* w4 = (const float4*)(td_W + (size_t)c*MD);
        const float4* g4 = (const float4*)tn_g;
        const float4* b4 = (const float4*)tn_beta;
        float sg = 0.f, sb = 0.f;
        short8 o;
        #pragma unroll
        for (int u = 0; u < 2; ++u) {
            int j4 = lane*2 + u;
            float4 w = w4[j4], g = g4[j4], bt = b4[j4];
            sg += w.x*g.x + w.y*g.y + w.z*g.z + w.w*g.w;
            sb += w.x*bt.x + w.y*bt.y + w.z*bt.z + w.w*bt.w;
            o[u*4+0] = (short)f2bf(w.x*g.x);
            o[u*4+1] = (short)f2bf(w.y*g.y);
            o[u*4+2] = (short)f2bf(w.z*g.z);
            o[u*4+3] = (short)f2bf(w.w*g.w);
        }
        // fragment-layout store: this thread holds k = lane*8..lane*8+7 of column c
        {
            int wvv = c >> 6, l15v = (c >> 2) & 15, ctv = c & 3;
            int ksv = lane >> 2, qv = lane & 3;   // k = lane*8+e -> ks = lane>>2, q = lane&3
            *(short8*)(tdwg_bf +
                ((((size_t)wvv*16 + ksv)*4 + ctv)*64 + (qv*16 + l15v))*8) = o;
        }
        #pragma unroll
        for (int dd = 32; dd > 0; dd >>= 1) {
            sg += __shfl_xor(sg, dd);
            sb += __shfl_xor(sb, dd);
        }
        if (lane == 0) { Gt[c] = sg; Bt[c] = sb + td_b[c]; }
        return;
    }

    __shared__ short ta[32][264];
    __shared__ float lsep[4][32][2];
    __shared__ float musig[32][2];

    int job, r0, cb, koff, BK;
    const float* Arow; const float* Brow;
    if (bid < 8) {
        job = 0; r0 = bid*32; cb = 0; koff = 0; BK = Dd;
        Arow = lembs; Brow = em_W;
    } else {
        int b2 = bid - 8;
        int half = b2 / 18;
        int b3 = b2 % 18;
        job = 1 + half;
        r0 = (b3 >> 1) * 32;
        cb = (b3 & 1) * 256;
        koff = half * 256; BK = MD;
        Arow = tlembs; Brow = tm_W;
    }

    {
        int row = tid >> 3, seg = (tid & 7) * 32;
        int r = r0 + row;
        if (r > 256) r = 256;
        const float4* s4 = (const float4*)(Arow + (size_t)r*Dd + seg);
        #pragma unroll
        for (int u = 0; u < 4; ++u) {
            float4 f0 = s4[u*2], f1 = s4[u*2+1];
            u32x4 pk;
            pk.x = bfpack(f0.x, f0.y);
            pk.y = bfpack(f0.z, f0.w);
            pk.z = bfpack(f1.x, f1.y);
            pk.w = bfpack(f1.z, f1.w);
            *(short8*)&ta[row][seg + u*8] = __builtin_bit_cast(short8, pk);
        }
    }
    __syncthreads();

    const float* bptr[4];
    #pragma unroll
    for (int ct = 0; ct < 4; ++ct) {
        int j = cb + wv*64 + ct*16 + l15;
        bptr[ct] = Brow + (size_t)j*BK + koff + q*8;
    }
    f32x4 acc[2][4];
    #pragma unroll
    for (int rt = 0; rt < 2; ++rt)
        #pragma unroll
        for (int ct = 0; ct < 4; ++ct)
            acc[rt][ct] = (f32x4){0.f,0.f,0.f,0.f};
    for (int ks = 0; ks < 8; ++ks) {
        short8 a0 = *(const short8*)&ta[ 0 + l15][ks*32 + q*8];
        short8 a1 = *(const short8*)&ta[16 + l15][ks*32 + q*8];
        short8 b[4];
        #pragma unroll
        for (int ct = 0; ct < 4; ++ct) {
            float4 f0 = *(const float4*)(bptr[ct] + ks*32);
            float4 f1 = *(const float4*)(bptr[ct] + ks*32 + 4);
            u32x4 pk;
            pk.x = bfpack(f0.x, f0.y);
            pk.y = bfpack(f0.z, f0.w);
            pk.z = bfpack(f1.x, f1.y);
            pk.w = bfpack(f1.z, f1.w);
            b[ct] = __builtin_bit_cast(short8, pk);
        }
        #pragma unroll
        for (int ct = 0; ct < 4; ++ct) {
            acc[0][ct] = __builtin_amdgcn_mfma_f32_16x16x32_bf16(a0, b[ct], acc[0][ct], 0,0,0);
            acc[1][ct] = __builtin_amdgcn_mfma_f32_16x16x32_bf16(a1, b[ct], acc[1][ct], 0,0,0);
        }
    }

    if (job != 0) {
        float* Pd = (job == 1) ? P0 : P1;
        #pragma unroll
        for (int rt = 0; rt < 2; ++rt) {
            #pragma unroll
            for (int reg = 0; reg < 4; ++reg) {
                int r = r0 + rt*16 + q*4 + reg;
                if (r < KP1) {
                    float* dst = Pd + (size_t)r*MD + cb + wv*64;
                    #pragma unroll
                    for (int ct = 0; ct < 4; ++ct)
                        dst[ct*16 + l15] = acc[rt][ct][reg];
                }
            }
        }
        return;
    }

    float bias_c[4];
    #pragma unroll
    for (int ct = 0; ct < 4; ++ct)
        bias_c[ct] = em_bias[wv*64 + ct*16 + l15];
    #pragma unroll
    for (int rt = 0; rt < 2; ++rt) {
        #pragma unroll
        for (int reg = 0; reg < 4; ++reg) {
            int r = r0 + rt*16 + q*4 + reg;
            #pragma unroll
            for (int ct = 0; ct < 4; ++ct) {
                float lv = lembs[(size_t)r*Dd + wv*64 + ct*16 + l15];
                acc[rt][ct][reg] = lv + fmaxf(acc[rt][ct][reg] + bias_c[ct], 0.f);
            }
        }
    }
    #pragma unroll
    for (int rt = 0; rt < 2; ++rt) {
        #pragma unroll
        for (int reg = 0; reg < 4; ++reg) {
            float s  = ((acc[rt][0][reg] + acc[rt][1][reg]) + (acc[rt][2][reg] + acc[rt][3][reg]));
            float ss = ((acc[rt][0][reg]*acc[rt][0][reg] + acc[rt][1][reg]*acc[rt][1][reg])
                      + (acc[rt][2][reg]*acc[rt][2][reg] + acc[rt][3][reg]*acc[rt][3][reg]));
            s  += __shfl_xor(s, 1);  ss += __shfl_xor(ss, 1);
            s  += __shfl_xor(s, 2);  ss += __shfl_xor(ss, 2);
            s  += __shfl_xor(s, 4);  ss += __shfl_xor(ss, 4);
            s  += __shfl_xor(s, 8);  ss += __shfl_xor(ss, 8);
            if (l15 == 0) {
                int rw = rt*16 + q*4 + reg;
                lsep[wv][rw][0] = s;
                lsep[wv][rw][1] = ss;
            }
        }
    }
    __syncthreads();
    if (tid < 32) {
        float s  = (lsep[0][tid][0] + lsep[1][tid][0]) + (lsep[2][tid][0] + lsep[3][tid][0]);
        float ss = (lsep[0][tid][1] + lsep[1][tid][1]) + (lsep[2][tid][1] + lsep[3][tid][1]);
        float mu = s * (1.f/Dd);
        musig[tid][0] = mu;
        musig[tid][1] = rsqrtf(ss*(1.f/Dd) - mu*mu + EPSf);
    }
    __syncthreads();
    float gl[4], bl[4];
    #pragma unroll
    for (int ct = 0; ct < 4; ++ct) {
        gl[ct] = em_g[wv*64 + ct*16 + l15];
        bl[ct] = em_beta[wv*64 + ct*16 + l15];
    }
    #pragma unroll
    for (int rt = 0; rt < 2; ++rt) {
        #pragma unroll
        for (int reg = 0; reg < 4; ++reg) {
            int rw = rt*16 + q*4 + reg;
            int r = r0 + rw;
            float mu = musig[rw][0], rs = musig[rw][1];
            unsigned short* dst = h_bf + (size_t)r*Dd + wv*64;
            #pragma unroll
            for (int ct = 0; ct < 4; ++ct)
                dst[ct*16 + l15] = f2bf((acc[rt][ct][reg] - mu)*rs*gl[ct] + bl[ct]);
        }
    }
}

// ---------------- K_em v6: LDS-staged B (coalesced dec_W reads, fragment-order LDS) ----------------
__global__ __launch_bounds__(256) void k_em_mfma6(
    const float* __restrict__ dec_W, const float* __restrict__ dec_b,
    const unsigned short* __restrict__ h_bf, float* __restrict__ part,
    unsigned short* __restrict__ E2)
{
    int kg = blockIdx.x, vb = blockIdx.y;   // kg fastest: adjacent blocks share dec_W slice
    int tid = threadIdx.x, lane = tid & 63, wv = tid >> 6;
    int l15 = lane & 15, q = lane >> 4;
    __shared__ short hs[64][264];           // A tile (33.8 KB)
    __shared__ short bs[4][4][512];         // B fragments for one ks slice (16 KB)

    {
        int row = tid >> 2, c0 = (tid & 3) * 64;
        const short8* src = (const short8*)(h_bf + (size_t)(kg*64 + row)*Dd + c0);
        #pragma unroll
        for (int u = 0; u < 8; ++u)
            *(short8*)&hs[row][c0 + u*8] = src[u];
    }

    // staging thread mapping: pass p covers rows p*32..p*32+31; 8 threads per row cover 32 k.
    int tr = tid >> 3, tc = tid & 7;
    int qv = tc >> 1, half = tc & 1;

    float4 pf[8];
    #pragma unroll
    for (int p = 0; p < 8; ++p) {
        int v = p*32 + tr;
        int vg = vb*256 + v;
        int vr = vg < Vv ? vg : Vv-1;
        pf[p] = *(const float4*)(dec_W + (size_t)vr*Dd + tc*4);
    }

    f32x4 acc[4][4];
    #pragma unroll
    for (int mt = 0; mt < 4; ++mt)
        #pragma unroll
        for (int ct = 0; ct < 4; ++ct)
            acc[mt][ct] = (f32x4){0.f,0.f,0.f,0.f};

    for (int ks = 0; ks < 8; ++ks) {
        __syncthreads();   // bs free (and pass 0: hs staged)
        #pragma unroll
        for (int p = 0; p < 8; ++p) {
            int v = p*32 + tr;
            int wvv = (v>>6)&3, ctv = v&3, l15v = (v>>2)&15;
            int s = qv*16 + l15v;
            int sl = s ^ ctv ^ ((s>>2)&12);          // bank-spread swizzle (bijective per (wvv,ctv))
            unsigned lo = bfpack(pf[p].x, pf[p].y);
            unsigned hi = bfpack(pf[p].z, pf[p].w);
            u32x2 w; w.x = lo; w.y = hi;
            *(u32x2*)&bs[wvv][ctv][sl*8 + half*4] = w;
        }
        __syncthreads();
        if (ks < 7) {       // prefetch next slice under this slice's MFMAs
            #pragma unroll
            for (int p = 0; p < 8; ++p) {
                int v = p*32 + tr;
                int vg = vb*256 + v;
                int vr = vg < Vv ? vg : Vv-1;
                pf[p] = *(const float4*)(dec_W + (size_t)vr*Dd + (ks+1)*32 + tc*4);
            }
        }
        short8 a[4], b[4];
        #pragma unroll
        for (int ct = 0; ct < 4; ++ct) {
            int sl = lane ^ ct ^ ((lane>>2)&12);
            b[ct] = *(const short8*)&bs[wv][ct][sl*8];
        }
        #pragma unroll
        for (int mt = 0; mt < 4; ++mt)
            a[mt] = *(const short8*)&hs[mt*16 + l15][ks*32 + q*8];
        #pragma unroll
        for (int mt = 0; mt < 4; ++mt)
            #pragma unroll
            for (int ct = 0; ct < 4; ++ct)
                acc[mt][ct] = __builtin_amdgcn_mfma_f32_16x16x32_bf16(a[mt], b[ct], acc[mt][ct], 0,0,0);
    }

    int vcol[4]; bool vok[4];
    #pragma unroll
    for (int ct = 0; ct < 4; ++ct) {
        int v = vb*256 + wv*64 + l15*4 + ct;
        vok[ct] = (v < Vv);
        vcol[ct] = v < Vv ? v : Vv-1;
    }
    #pragma unroll
    for (int ct = 0; ct < 4; ++ct) {
        if (vok[ct]) {
            float db = dec_b[vcol[ct]];
            #pragma unroll
            for (int mt = 0; mt < 4; ++mt)
                #pragma unroll
                for (int reg = 0; reg < 4; ++reg)
                    acc[mt][ct][reg] += db;
        } else {
            #pragma unroll
            for (int mt = 0; mt < 4; ++mt)
                #pragma unroll
                for (int reg = 0; reg < 4; ++reg)
                    acc[mt][ct][reg] = -1e30f;
        }
    }
    #pragma unroll
    for (int mt = 0; mt < 4; ++mt) {
        #pragma unroll
        for (int reg = 0; reg < 4; ++reg) {
            int k = kg*64 + mt*16 + q*4 + reg;
            u32x2 p;
            p.x = f2bf2(acc[mt][0][reg], acc[mt][1][reg]);
            p.y = f2bf2(acc[mt][2][reg], acc[mt][3][reg]);
            *(u32x2*)(E2 + (size_t)k*VPAD + vb*256 + wv*64 + l15*4) = p;
        }
    }
    #pragma unroll
    for (int mt = 0; mt < 4; ++mt) {
        #pragma unroll
        for (int reg = 0; reg < 4; ++reg) {
            float m = fmaxf(fmaxf(acc[mt][0][reg], acc[mt][1][reg]),
                            fmaxf(acc[mt][2][reg], acc[mt][3][reg]));
            m = fmaxf(m, __shfl_xor(m, 1));
            m = fmaxf(m, __shfl_xor(m, 2));
            m = fmaxf(m, __shfl_xor(m, 4));
            m = fmaxf(m, __shfl_xor(m, 8));
            float s = __expf(acc[mt][0][reg] - m) + __expf(acc[mt][1][reg] - m)
                    + __expf(acc[mt][2][reg] - m) + __expf(acc[mt][3][reg] - m);
            s += __shfl_xor(s, 1);
            s += __shfl_xor(s, 2);
            s += __shfl_xor(s, 4);
            s += __shfl_xor(s, 8);
            if (l15 == 0) {
                int k = kg*64 + mt*16 + q*4 + reg;
                part[((size_t)k*VB3 + vb*4 + wv)*2]     = m;
                part[((size_t)k*VB3 + vb*4 + wv)*2 + 1] = s;
            }
        }
    }
}

// ---------------- K_comb: combine partials -> lse_em[k] (unchanged) ----------------
__global__ __launch_bounds__(64) void k_em_comb3(
    const float* __restrict__ part, float* __restrict__ lse_em)
{
    int k = blockIdx.x, lane = threadIdx.x;
    float m = -1e30f, s = 0.f;
    for (int vb = lane; vb < VB3; vb += 64) {
        float m2 = part[((size_t)k*VB3+vb)*2], s2 = part[((size_t)k*VB3+vb)*2+1];
        if (m2 > m) { s = s*__expf(m - m2) + s2; m = m2; }
        else          s += s2*__expf(m2 - m);
    }
    #pragma unroll
    for (int d = 1; d < 64; d <<= 1) {
        float mo = __shfl_xor(m, d), so = __shfl_xor(s, d);
        float mn = fmaxf(m, mo);
        s = s*__expf(m - mn) + so*__expf(mo - mn);
        m = mn;
    }
    if (lane == 0) lse_em[k] = m + logf(s);
}

// ---------------- K_trans10: fragment-layout B loads (contiguous 1KB/inst) ----------------
__global__ __launch_bounds__(256, 4) void k_trans10(
    const float* __restrict__ tlembs, const float* __restrict__ P0,
    const float* __restrict__ P1, const float* __restrict__ tm_bias,
    const short* __restrict__ tdwg_bf, const float* __restrict__ Gt,
    const float* __restrict__ Bt, float* __restrict__ lse_t,
    unsigned short* __restrict__ Td)
{
    __shared__ short th[32][520];
    __shared__ float musig[32][2];
    __shared__ float lsep[4][32][2];
    int tid = threadIdx.x, lane = tid & 63, wv = tid >> 6;
    int l15 = lane & 15, q = lane >> 4;
    int r0 = blockIdx.x * 32;

    // ---- stage + LN stats fused ----
    {
        const float4* bias0 = (const float4*)tm_bias;
        const float4* bias1 = (const float4*)(tm_bias + 256);
        float4 c0 = bias0[lane], c1 = bias1[lane];
        #pragma unroll
        for (int i = 0; i < 8; ++i) {
            int row = wv*8 + i;
            int r = r0 + row; if (r >= NROWS) r = NROWS - 1;
            int i0 = r / KP1, i1 = r - i0*KP1;
            float4 a0 = ((const float4*)(P0 + (size_t)i0*MD))[lane];
            float4 b0 = ((const float4*)(P1 + (size_t)i1*MD))[lane];
            float4 t0 = ((const float4*)(tlembs + (size_t)i0*Dd))[lane];
            float4 a1 = ((const float4*)(P0 + (size_t)i0*MD + 256))[lane];
            float4 b1 = ((const float4*)(P1 + (size_t)i1*MD + 256))[lane];
            float4 t1 = ((const float4*)(tlembs + (size_t)i1*Dd))[lane];
            float v0 = t0.x + fmaxf(a0.x+b0.x+c0.x, 0.f);
            float v1 = t0.y + fmaxf(a0.y+b0.y+c0.y, 0.f);
            float v2 = t0.z + fmaxf(a0.z+b0.z+c0.z, 0.f);
            float v3 = t0.w + fmaxf(a0.w+b0.w+c0.w, 0.f);
            float v4 = t1.x + fmaxf(a1.x+b1.x+c1.x, 0.f);
            float v5 = t1.y + fmaxf(a1.y+b1.y+c1.y, 0.f);
            float v6 = t1.z + fmaxf(a1.z+b1.z+c1.z, 0.f);
            float v7 = t1.w + fmaxf(a1.w+b1.w+c1.w, 0.f);
            u32x2 p0; p0.x = bfpack(v0, v1); p0.y = bfpack(v2, v3);
            u32x2 p1; p1.x = bfpack(v4, v5); p1.y = bfpack(v6, v7);
            *(u32x2*)&th[row][lane*4]       = p0;
            *(u32x2*)&th[row][256 + lane*4] = p1;
            float s  = ((v0+v1)+(v2+v3)) + ((v4+v5)+(v6+v7));
            float ss = ((v0*v0+v1*v1)+(v2*v2+v3*v3)) + ((v4*v4+v5*v5)+(v6*v6+v7*v7));
            #pragma unroll
            for (int d = 1; d < 64; d <<= 1) {
                s  += __shfl_xor(s, d);
                ss += __shfl_xor(ss, d);
            }
            if (lane == 0) {
                float mu = s * (1.f/MD);
                musig[row][0] = mu;
                musig[row][1] = rsqrtf(ss*(1.f/MD) - mu*mu + EPSf);
            }
        }
    }
    __syncthreads();

    // ---- MFMA; B from fragment-layout tdwgP: per (ks,ct) one contiguous 1KB load ----
    f32x4 acc[2][4];
    #pragma unroll
    for (int rt = 0; rt < 2; ++rt)
        #pragma unroll
        for (int ct = 0; ct < 4; ++ct)
            acc[rt][ct] = (f32x4){0.f, 0.f, 0.f, 0.f};
    const short* bb = tdwg_bf + (size_t)wv*32768 + (size_t)lane*8;  // wv*16*4*64*8
    short8 nb0 = *(const short8*)(bb);
    short8 nb1 = *(const short8*)(bb + 512);
    short8 nb2 = *(const short8*)(bb + 1024);
    short8 nb3 = *(const short8*)(bb + 1536);
    #pragma unroll
    for (int ks = 0; ks < 16; ++ks) {
        short8 b0 = nb0, b1 = nb1, b2 = nb2, b3 = nb3;
        if (ks < 15) {
            const short* nxt = bb + (size_t)(ks+1)*2048;
            nb0 = *(const short8*)(nxt);
            nb1 = *(const short8*)(nxt + 512);
            nb2 = *(const short8*)(nxt + 1024);
            nb3 = *(const short8*)(nxt + 1536);
        }
        int ko = ks*32 + q*8;
        short8 a0 = *(const short8*)&th[ 0 + l15][ko];
        short8 a1 = *(const short8*)&th[16 + l15][ko];
        acc[0][0] = __builtin_amdgcn_mfma_f32_16x16x32_bf16(a0, b0, acc[0][0], 0,0,0);
        acc[1][0] = __builtin_amdgcn_mfma_f32_16x16x32_bf16(a1, b0, acc[1][0], 0,0,0);
        acc[0][1] = __builtin_amdgcn_mfma_f32_16x16x32_bf16(a0, b1, acc[0][1], 0,0,0);
        acc[1][1] = __builtin_amdgcn_mfma_f32_16x16x32_bf16(a1, b1, acc[1][1], 0,0,0);
        acc[0][2] = __builtin_amdgcn_mfma_f32_16x16x32_bf16(a0, b2, acc[0][2], 0,0,0);
        acc[1][2] = __builtin_amdgcn_mfma_f32_16x16x32_bf16(a1, b2, acc[1][2], 0,0,0);
        acc[0][3] = __builtin_amdgcn_mfma_f32_16x16x32_bf16(a0, b3, acc[0][3], 0,0,0);
        acc[1][3] = __builtin_amdgcn_mfma_f32_16x16x32_bf16(a1, b3, acc[1][3], 0,0,0);
    }

    // ---- LN apply + packed contiguous Td stores + softmax partials ----
    float4 Gc = *(const float4*)(Gt + wv*64 + l15*4);
    float4 Bc = *(const float4*)(Bt + wv*64 + l15*4);
    #pragma unroll
    for (int rt = 0; rt < 2; ++rt) {
        #pragma unroll
        for (int reg = 0; reg < 4; ++reg) {
            int rw = rt*16 + q*4 + reg;
            float mu = musig[rw][0], rs = musig[rw][1];
            float e0 = rs*(acc[rt][0][reg] - mu*Gc.x) + Bc.x;
            float e1 = rs*(acc[rt][1][reg] - mu*Gc.y) + Bc.y;
            float e2 = rs*(acc[rt][2][reg] - mu*Gc.z) + Bc.z;
            float e3 = rs*(acc[rt][3][reg] - mu*Gc.w) + Bc.w;
            long r = (long)r0 + rw;
            if (r < NROWS) {
                u32x2 p;
                p.x = f2bf2(e0, e1);
                p.y = f2bf2(e2, e3);
                *(u32x2*)(Td + (size_t)r*Kst + wv*64 + l15*4) = p;
            }
            float m = fmaxf(fmaxf(e0, e1), fmaxf(e2, e3));
            m = fmaxf(m, __shfl_xor(m, 1));
            m = fmaxf(m, __shfl_xor(m, 2));
            m = fmaxf(m, __shfl_xor(m, 4));
            m = fmaxf(m, __shfl_xor(m, 8));
            float s = __expf(e0 - m) + __expf(e1 - m) + __expf(e2 - m) + __expf(e3 - m);
            s += __shfl_xor(s, 1);
            s += __shfl_xor(s, 2);
            s += __shfl_xor(s, 4);
            s += __shfl_xor(s, 8);
            if (l15 == 0) {
                lsep[wv][rw][0] = m;
                lsep[wv][rw][1] = s;
            }
        }
    }
    __syncthreads();
    if (tid < 32) {
        int r = r0 + tid;
        if (r < NROWS) {
            float m0 = lsep[0][tid][0], m1 = lsep[1][tid][0];
            float m2 = lsep[2][tid][0], m3 = lsep[3][tid][0];
            float mg = fmaxf(fmaxf(m0, m1), fmaxf(m2, m3));
            float s = lsep[0][tid][1]*__expf(m0-mg) + lsep[1][tid][1]*__expf(m1-mg)
                    + lsep[2][tid][1]*__expf(m2-mg) + lsep[3][tid][1]*__expf(m3-mg);
            lse_t[r] = mg + logf(s);
        }
    }
}

// ---------------- K_gather: 4 timesteps per thread, 1 atomic ----------------
#define GT_CH 4
__global__ __launch_bounds__(256) void k_gather3(
    const int* __restrict__ x, const int* __restrict__ z,
    const unsigned short* __restrict__ E2, const float* __restrict__ lse_em,
    const unsigned short* __restrict__ Td, const float* __restrict__ lse_t,
    float* __restrict__ out)
{
    int b = threadIdx.x;
    int t0 = blockIdx.x * GT_CH;
    float accv = 0.f;
    #pragma unroll
    for (int u = 0; u < GT_CH; ++u) {
        int t = t0 + u;
        int zc = z[t*Bb + b];
        int xv = x[t*Bb + b];
        int i0 = (t >= 2) ? z[(t-2)*Bb + b] : Kst;
        int i1 = (t >= 1) ? z[(t-1)*Bb + b] : Kst;
        int lin = i0*KP1 + i1;
        accv += bf2f(E2[(size_t)zc*VPAD + xv]) - lse_em[zc]
              + bf2f(Td[(size_t)lin*Kst + zc]) - lse_t[lin];
    }
    atomicAdd(&out[b], accv);
}

extern "C" void kernel_launch(void* const* d_in, const int* in_sizes, int n_in,
                              void* d_out, int out_size, void* d_ws, size_t ws_size,
                              hipStream_t stream)
{
    const int*   x       = (const int*)  d_in[0];
    const int*   z       = (const int*)  d_in[1];
    const float* lembs   = (const float*)d_in[2];
    const float* tlembs  = (const float*)d_in[3];
    const float* dec_W   = (const float*)d_in[4];
    const float* dec_b   = (const float*)d_in[5];
    const float* em_W    = (const float*)d_in[6];
    const float* em_bias = (const float*)d_in[7];
    const float* em_g    = (const float*)d_in[8];
    const float* em_beta = (const float*)d_in[9];
    const float* td_W    = (const float*)d_in[10];
    const float* td_b    = (const float*)d_in[11];
    const float* tm_W    = (const float*)d_in[12];
    const float* tm_bias = (const float*)d_in[13];
    const float* tn_g    = (const float*)d_in[14];
    const float* tn_beta = (const float*)d_in[15];
    float* out = (float*)d_out;

    float* ws     = (float*)d_ws;
    float* P0     = ws;                    // 131584
    float* P1     = P0 + 131584;           // 131584
    float* lse_em = P1 + 131584;           // 256
    float* part   = lse_em + 256;          // 256*784*2 = 401408
    float* lse_t  = part + 401408;         // 66052
    float* Gt     = lse_t + 66052;         // 256
    float* Bt     = Gt + 256;              // 256
    unsigned short* tdwg_bf = (unsigned short*)(Bt + 256);      // 131072 ushort (fragment layout)
    unsigned short* h_bf   = tdwg_bf + 131072;                  // 65536 ushort
    unsigned short* E2     = h_bf + 65536;                      // 256*50176 ushort (25.7MB)
    unsigned short* Td     = E2 + (size_t)Kst*VPAD;             // 66049*256 ushort (33.8MB)

    hipMemsetAsync(out, 0, Bb*sizeof(float), stream);
    k_hP<<<108, 256, 0, stream>>>(lembs, em_W, em_bias, em_g, em_beta, h_bf,
                                  tlembs, tm_W, P0, P1,
                                  td_W, tn_g, tn_beta, td_b, tdwg_bf, Gt, Bt);
    k_em_mfma6<<<dim3(4, VB2), 256, 0, stream>>>(dec_W, dec_b, h_bf, part, E2);
    k_em_comb3<<<Kst, 64, 0, stream>>>(part, lse_em);
    k_trans10<<<(NROWS + 31)/32, 256, 0, stream>>>(tlembs, P0, P1, tm_bias,
                                                   (const short*)tdwg_bf, Gt, Bt,
                                                   lse_t, Td);
    k_gather3<<<Tt/GT_CH, 256, 0, stream>>>(x, z, E2, lse_em, Td, lse_t, out);
}